// Round 10
// baseline (479.184 us; speedup 1.0000x reference)
//
#include <hip/hip_runtime.h>
#include <hip/hip_bf16.h>

typedef __attribute__((ext_vector_type(8))) short short8;
typedef __attribute__((ext_vector_type(4))) float f32x4;

// pack 8 fp32 -> 8 bf16 (RNE) as one short8 (4 VGPRs)
__device__ __forceinline__ short8 pack8(const f32x4& a, const f32x4& b) {
    union { __hip_bfloat162 h[4]; short8 s; } u;
    u.h[0] = __float22bfloat162_rn(make_float2(a[0], a[1]));
    u.h[1] = __float22bfloat162_rn(make_float2(a[2], a[3]));
    u.h[2] = __float22bfloat162_rn(make_float2(b[0], b[1]));
    u.h[3] = __float22bfloat162_rn(make_float2(b[2], b[3]));
    return u.s;
}

// r2..r7-proven involution swizzle (fallback kernel only)
__device__ __forceinline__ int swz4(int g) { return g ^ (((g >> 4) & 3) << 1); }

// async global->LDS DMA, 16B per lane; LDS dest = wave-uniform base + lane*16
#define GLDS(GP, LP)                                                          \
    __builtin_amdgcn_global_load_lds(                                         \
        (__attribute__((address_space(1))) void*)(void*)(GP),                 \
        (__attribute__((address_space(3))) void*)(void*)(LP), 16, 0, 0)

// ============================================================================
// Kernel 1 (r9-proven): fp32 -> bf16 conversion + MFMA-granule relayout.
// Granule (idx, ks) = 1KB: lane l holds row idx*16+(l&15), k ks*32+(l>>4)*8..+8.
// W1b: [km][f 0..31][ks 0..15]; Xb (at +134217728 shorts): [mf 0..63][ks].
// ============================================================================
__global__ __launch_bounds__(256)
void ens_cvt(const float* __restrict__ X, const float* __restrict__ W1,
             short* __restrict__ WS)
{
    const int t = threadIdx.x, lane = t & 63, wv = t >> 6;
    const int g = blockIdx.x * 4 + wv;
    const int row16 = lane & 15, koct = lane >> 4;
    const float* src;
    short* dst;
    if (blockIdx.x < 4096) {                       // W1: g = km*32 + f
        const int km = g >> 5, f = g & 31;
        src = W1 + (size_t)km * 262144 + (size_t)(f * 16 + row16) * 512 + koct * 8;
        dst = WS + (size_t)km * 262144 + (size_t)(f * 16) * 512 + lane * 8;
    } else {                                       // X: mf = g - 16384 (0..63)
        const int mf = g - 16384;
        src = X + (size_t)(mf * 16 + row16) * 512 + koct * 8;
        dst = WS + 134217728ull + (size_t)(mf * 16) * 512 + lane * 8;
    }
#pragma unroll
    for (int ks = 0; ks < 16; ++ks) {
        f32x4 a = *(const f32x4*)(src + ks * 32);
        f32x4 b = *(const f32x4*)(src + ks * 32 + 4);
        *(short8*)(dst + ks * 512) = pack8(a, b);
    }
}

// ============================================================================
// Kernel 2: m201-port bf16 GEMM. BK=64, 2x64KB LDS K-tile dbuf, 4 phases/tile:
// each phase = {ds_read quadrant (av x4 [+bv x4 when new kk]) | 4 GLDS issue
// (phases 0,1 only: front-loads all 8 staging loads of tile kt+1) -> barrier
// -> lgkmcnt(0)+sched_barrier -> setprio(1) 16 MFMA setprio(0) -> barrier}.
// Tile boundary: per-wave vmcnt(0) BEFORE the phase-3 closing barrier (loads
// were issued >=2 phases (~>1500 cyc MFMA) earlier -> drain is covered; the
// barrier then publishes all waves' staging cross-wave).
// Race audit: GLDS during kt write buf[(kt+1)&1]; reads during kt are from
// buf[kt&1]. Staging of kt (issued at kt-1 ph0/ph1) was drained+barriered at
// kt-1 ph3. No ds_writes exist; granule reads are linear lane*16 -> conflict-
// free by construction (r9: 3.9e5 total).
// ============================================================================
#define PH(MH, KK, DOI, DOVM)                                                 \
  do {                                                                        \
    _Pragma("unroll") for (int ii = 0; ii < 4; ++ii)                          \
        av[ii] = *(const short8*)(rb +                                        \
            (((wm * 8 + (MH) * 4 + ii) * 2 + (KK)) << 10) + l16);             \
    if ((MH) == 0) {                                                          \
      _Pragma("unroll") for (int pp = 0; pp < 4; ++pp)                        \
          bv[pp] = *(const short8*)(rb + 32768 +                              \
              (((wn * 4 + pp) * 2 + (KK)) << 10) + l16);                      \
    }                                                                         \
    if ((DOI) == 1) {                                                         \
      GLDS(g0 + koff, wb + d0); GLDS(g1 + koff, wb + d1);                     \
      GLDS(g2 + koff, wb + d2); GLDS(g3 + koff, wb + d3);                     \
    } else if ((DOI) == 2) {                                                  \
      GLDS(g4 + koff, wb + d4); GLDS(g5 + koff, wb + d5);                     \
      GLDS(g6 + koff, wb + d6); GLDS(g7 + koff, wb + d7);                     \
    }                                                                         \
    __builtin_amdgcn_s_barrier();                                             \
    asm volatile("s_waitcnt lgkmcnt(0)" ::: "memory");                        \
    __builtin_amdgcn_sched_barrier(0);                                        \
    __builtin_amdgcn_s_setprio(1);                                            \
    _Pragma("unroll") for (int ii = 0; ii < 4; ++ii)                          \
        _Pragma("unroll") for (int pp = 0; pp < 4; ++pp)                      \
            acc[(MH) * 4 + ii][pp] = __builtin_amdgcn_mfma_f32_16x16x32_bf16( \
                av[ii], bv[pp], acc[(MH) * 4 + ii][pp], 0, 0, 0);             \
    __builtin_amdgcn_s_setprio(0);                                            \
    __builtin_amdgcn_sched_barrier(0);                                        \
    if (DOVM) asm volatile("s_waitcnt vmcnt(0)" ::: "memory");                \
    __builtin_amdgcn_s_barrier();                                             \
  } while (0)

__global__ __launch_bounds__(512, 2)
void ens_gemm_dma(const short* __restrict__ Xb, const short* __restrict__ W1b,
                  const float* __restrict__ B1, const float* __restrict__ W2,
                  const float* __restrict__ B2, float* __restrict__ out)
{
    extern __shared__ char smem[];
    const int t    = threadIdx.x;
    const int lane = t & 63;
    const int l16  = lane << 4;
    const int wv   = t >> 6;
    const int wm   = wv >> 2;     // 0..1
    const int wn   = wv & 3;      // 0..3

    // XCD-aware decode: 8 blocks of the same km adjacent on one XCD.
    const int bb  = blockIdx.x;
    const int xcd = bb & 7;
    const int j   = bb >> 3;
    const int km  = xcd * 64 + (j >> 3);   // 0..511
    const int sub = j & 7;
    const int mt  = sub >> 1;              // 0..3 (256-row batch tile)
    const int nt  = sub & 1;               // 0..1 (256-col n half)

    // DMA staging: wave wv owns granules g = wv*8+q (q 0..7); op=g>>5 (A/B),
    // ri=(g>>1)&15 (16-row group), kk=g&1 (K-half of the BK=64 tile).
    // src granule [idx][ks]: idx*8192 + ks*512 shorts; ks = tile*2 + kk.
    const short* g0; const short* g1; const short* g2; const short* g3;
    const short* g4; const short* g5; const short* g6; const short* g7;
    int d0, d1, d2, d3, d4, d5, d6, d7;
    {
        auto gsrc = [&](int q, int& d) -> const short* {
            int g  = wv * 8 + q;
            int op = g >> 5, ri = (g >> 1) & 15, kk = g & 1;
            d = op * 32768 + ((ri * 2 + kk) << 10);
            const short* base = (op == 0)
                ? Xb + (size_t)(mt * 16 + ri) * 8192
                : W1b + (size_t)km * 262144 + (size_t)(nt * 16 + ri) * 8192;
            return base + kk * 512 + lane * 8;
        };
        g0 = gsrc(0, d0); g1 = gsrc(1, d1); g2 = gsrc(2, d2); g3 = gsrc(3, d3);
        g4 = gsrc(4, d4); g5 = gsrc(5, d5); g6 = gsrc(6, d6); g7 = gsrc(7, d7);
    }

    f32x4 acc[8][4];
#pragma unroll
    for (int i = 0; i < 8; ++i)
#pragma unroll
        for (int p = 0; p < 4; ++p)
            acc[i][p] = (f32x4)0.0f;

    short8 av[4], bv[4];

    // ---- prologue: stage tile 0 into buf0, drain, publish ----
    {
        char* wb = smem;
        GLDS(g0, wb + d0); GLDS(g1, wb + d1); GLDS(g2, wb + d2); GLDS(g3, wb + d3);
        GLDS(g4, wb + d4); GLDS(g5, wb + d5); GLDS(g6, wb + d6); GLDS(g7, wb + d7);
        asm volatile("s_waitcnt vmcnt(0)" ::: "memory");
        __builtin_amdgcn_sched_barrier(0);
        __builtin_amdgcn_s_barrier();
    }

#pragma unroll 1
    for (int kt = 0; kt < 7; ++kt) {
        const char* rb = smem + (kt & 1) * 65536;
        char* wb       = smem + ((kt + 1) & 1) * 65536;
        const int koff = (kt + 1) << 10;   // shorts: 2 granules per tile step

        PH(0, 0, 1, 0);   // quadrant (mi 0-3, kk0); issue staging q0..q3
        PH(1, 0, 2, 0);   // quadrant (mi 4-7, kk0); issue staging q4..q7
        PH(0, 1, 0, 0);   // quadrant (mi 0-3, kk1)
        PH(1, 1, 0, 1);   // quadrant (mi 4-7, kk1); drain+publish boundary
    }
    {   // kt = 7: compute only
        const char* rb = smem + 65536;
        char* wb = smem;           // unused (DOI=0)
        const int koff = 0;        // unused
        (void)wb; (void)koff;
        PH(0, 0, 0, 0);
        PH(1, 0, 0, 0);
        PH(0, 1, 0, 0);
        PH(1, 1, 0, 0);
    }

    // ---- fused epilogue (r6-proven): relu + dot(W2) partials + scatter ----
    const int nc = lane & 15;
    const int kq = lane >> 4;
    float b1v[4], w2v[4];
#pragma unroll
    for (int pp = 0; pp < 4; ++pp) {
        int n = nt * 256 + (wn * 4 + pp) * 16 + nc;
        b1v[pp] = B1[km * 512 + n];
        w2v[pp] = W2[km * 512 + n];
    }

    float* lout = (float*)smem;   // buf0; last buf0 reads (kt=6) long synced
#pragma unroll
    for (int i = 0; i < 8; ++i) {
#pragma unroll
        for (int r = 0; r < 4; ++r) {
            float s = 0.f;
#pragma unroll
            for (int pp = 0; pp < 4; ++pp) {
                float h = acc[i][pp][r] + b1v[pp];
                h = h > 0.f ? h : 0.f;
                s += h * w2v[pp];
            }
#pragma unroll
            for (int d = 1; d < 16; d <<= 1)
                s += __shfl_xor(s, d, 64);
            if (nc == 0) {
                int row = wm * 128 + i * 16 + kq * 4 + r;
                lout[row * 4 + wn] = s;
            }
        }
    }
    __syncthreads();
    if (t < 256) {
        float s = lout[t * 4 + 0] + lout[t * 4 + 1] + lout[t * 4 + 2] + lout[t * 4 + 3];
        if (nt == 0) s += B2[km];
        int b = mt * 256 + t;
        // out[b, e, o] with k = o*E + e  ->  flat b*512 + (km%8)*64 + (km/8)
        atomicAdd(out + (size_t)b * 512 + (km & 7) * 64 + (km >> 3), s);
    }
}

// ============================================================================
// Fallback (r6 verbatim, 428 µs): used when ws_size < 269,484,032 bytes.
// ============================================================================
#define FISSUE(S, BASE, KT1)                                                  \
  do {                                                                        \
    const float* q_ = (BASE) + (KT1) * 64;                                    \
    S[0] = *(const f32x4*)q_;          S[1] = *(const f32x4*)(q_ + 4);        \
    S[2] = *(const f32x4*)(q_ + 32);   S[3] = *(const f32x4*)(q_ + 36);       \
    const float* q2_ = q_ + 65536;                                            \
    S[4] = *(const f32x4*)q2_;         S[5] = *(const f32x4*)(q2_ + 4);       \
    S[6] = *(const f32x4*)(q2_ + 32);  S[7] = *(const f32x4*)(q2_ + 36);      \
  } while (0)

#define FWRITEB(S, WB, OPOFF)                                                 \
  do {                                                                        \
    char* d0_ = (WB) + (OPOFF) + wfrag;                                       \
    *(short8*)d0_ = pack8(S[0], S[1]);                                        \
    *(short8*)(d0_ + 1024) = pack8(S[2], S[3]);                               \
    char* d1_ = d0_ + 16384;                                                  \
    *(short8*)d1_ = pack8(S[4], S[5]);                                        \
    *(short8*)(d1_ + 1024) = pack8(S[6], S[7]);                               \
  } while (0)

#define FKK(RB, KKV)                                                          \
  do {                                                                        \
    _Pragma("unroll") for (int mi = 0; mi < 8; ++mi)                          \
        av[mi] = *(const short8*)((RB) +                                      \
            (((wm * 8 + mi) * 2 + (KKV)) << 10) + rdo);                       \
    _Pragma("unroll") for (int pp = 0; pp < 4; ++pp)                          \
        bv[pp] = *(const short8*)((RB) + 32768 +                              \
            (((wn * 4 + pp) * 2 + (KKV)) << 10) + rdo);                       \
    __builtin_amdgcn_s_setprio(1);                                            \
    _Pragma("unroll") for (int mi = 0; mi < 8; ++mi)                          \
        _Pragma("unroll") for (int pp = 0; pp < 4; ++pp)                      \
            acc[mi][pp] = __builtin_amdgcn_mfma_f32_16x16x32_bf16(            \
                av[mi], bv[pp], acc[mi][pp], 0, 0, 0);                        \
    __builtin_amdgcn_s_setprio(0);                                            \
  } while (0)

#define FPRO_WRITE(TT, ROFF)                                                  \
  do {                                                                        \
    short8 a_ = pack8(TT[0], TT[1]);                                          \
    short8 b_ = pack8(TT[2], TT[3]);                                          \
    char* d_ = smem + (ROFF) + wfrag;                                         \
    *(short8*)d_ = a_;                                                        \
    *(short8*)(d_ + 1024) = b_;                                               \
  } while (0)

__global__ __launch_bounds__(512, 2)
void ens_mlp_fallback(const float* __restrict__ X,
                      const float* __restrict__ W1,
                      const float* __restrict__ B1,
                      const float* __restrict__ W2,
                      const float* __restrict__ B2,
                      float* __restrict__ out)
{
    extern __shared__ char smem[];
    const int t    = threadIdx.x;
    const int lane = t & 63;
    const int wv   = t >> 6;
    const int wm   = wv >> 2;
    const int wn   = wv & 3;

    const int bb  = blockIdx.x;
    const int xcd = bb & 7;
    const int j   = bb >> 3;
    const int km  = xcd * 64 + (j >> 3);
    const int sub = j & 7;
    const int mt  = sub >> 1;
    const int nt  = sub & 1;

    const float* __restrict__ W1k = W1 + (size_t)km * (512 * 512);

    const int lr = t >> 2;
    const int c  = t & 3;
    const float* As = X   + (size_t)(mt * 256 + lr) * 512 + c * 8;
    const float* Bs = W1k + (size_t)(nt * 256 + lr) * 512 + c * 8;
    const int wfrag = ((lr >> 4) << 11) + (swz4((c << 4) | (lr & 15)) << 4);
    const int rdo   = swz4(lane) << 4;

    {
        f32x4 t0[4], t1[4], t2[4], t3[4];
        const float* q;
        q = As;          t0[0]=*(const f32x4*)q; t0[1]=*(const f32x4*)(q+4); t0[2]=*(const f32x4*)(q+32); t0[3]=*(const f32x4*)(q+36);
        q = As + 65536;  t1[0]=*(const f32x4*)q; t1[1]=*(const f32x4*)(q+4); t1[2]=*(const f32x4*)(q+32); t1[3]=*(const f32x4*)(q+36);
        q = Bs;          t2[0]=*(const f32x4*)q; t2[1]=*(const f32x4*)(q+4); t2[2]=*(const f32x4*)(q+32); t2[3]=*(const f32x4*)(q+36);
        q = Bs + 65536;  t3[0]=*(const f32x4*)q; t3[1]=*(const f32x4*)(q+4); t3[2]=*(const f32x4*)(q+32); t3[3]=*(const f32x4*)(q+36);
        asm volatile("s_waitcnt vmcnt(12)" ::: "memory"); FPRO_WRITE(t0, 0);
        asm volatile("s_waitcnt vmcnt(8)"  ::: "memory"); FPRO_WRITE(t1, 16384);
        asm volatile("s_waitcnt vmcnt(4)"  ::: "memory"); FPRO_WRITE(t2, 32768);
        asm volatile("s_waitcnt vmcnt(0)"  ::: "memory"); FPRO_WRITE(t3, 49152);
        asm volatile("s_waitcnt lgkmcnt(0)" ::: "memory");
        __builtin_amdgcn_sched_barrier(0);
        __builtin_amdgcn_s_barrier();
    }

    f32x4 acc[8][4];
#pragma unroll
    for (int i = 0; i < 8; ++i)
#pragma unroll
        for (int p = 0; p < 4; ++p)
            acc[i][p] = (f32x4)0.0f;

    short8 av[8], bv[4];
    f32x4 sS[8];

#pragma unroll 1
    for (int kt = 0; kt < 7; ++kt) {
        const char* rb = smem + (kt & 1) * 65536;
        char* wb       = smem + ((kt + 1) & 1) * 65536;

        FISSUE(sS, Bs, kt + 1);
        FKK(rb, 0);
        asm volatile("s_waitcnt vmcnt(0)" ::: "memory");
        FWRITEB(sS, wb, 32768);
        FISSUE(sS, As, kt + 1);
        FKK(rb, 1);
        asm volatile("s_waitcnt vmcnt(0)" ::: "memory");
        FWRITEB(sS, wb, 0);
        asm volatile("s_waitcnt lgkmcnt(0)" ::: "memory");
        __builtin_amdgcn_sched_barrier(0);
        __builtin_amdgcn_s_barrier();
    }
    {
        const char* rb = smem + 65536;
        FKK(rb, 0);
        FKK(rb, 1);
    }

    const int nc = lane & 15;
    const int kq = lane >> 4;
    float b1v[4], w2v[4];
#pragma unroll
    for (int pp = 0; pp < 4; ++pp) {
        int n = nt * 256 + (wn * 4 + pp) * 16 + nc;
        b1v[pp] = B1[km * 512 + n];
        w2v[pp] = W2[km * 512 + n];
    }

    float* lout = (float*)smem;
#pragma unroll
    for (int i = 0; i < 8; ++i) {
#pragma unroll
        for (int r = 0; r < 4; ++r) {
            float s = 0.f;
#pragma unroll
            for (int pp = 0; pp < 4; ++pp) {
                float h = acc[i][pp][r] + b1v[pp];
                h = h > 0.f ? h : 0.f;
                s += h * w2v[pp];
            }
#pragma unroll
            for (int d = 1; d < 16; d <<= 1)
                s += __shfl_xor(s, d, 64);
            if (nc == 0) {
                int row = wm * 128 + i * 16 + kq * 4 + r;
                lout[row * 4 + wn] = s;
            }
        }
    }
    __syncthreads();
    if (t < 256) {
        float s = lout[t * 4 + 0] + lout[t * 4 + 1] + lout[t * 4 + 2] + lout[t * 4 + 3];
        if (nt == 0) s += B2[km];
        int b = mt * 256 + t;
        atomicAdd(out + (size_t)b * 512 + (km & 7) * 64 + (km >> 3), s);
    }
}

extern "C" void kernel_launch(void* const* d_in, const int* in_sizes, int n_in,
                              void* d_out, int out_size, void* d_ws, size_t ws_size,
                              hipStream_t stream) {
    const float* X  = (const float*)d_in[0];
    const float* W1 = (const float*)d_in[1];
    const float* B1 = (const float*)d_in[2];
    const float* W2 = (const float*)d_in[3];
    const float* B2 = (const float*)d_in[4];
    float* out = (float*)d_out;

    hipMemsetAsync(out, 0, (size_t)out_size * sizeof(float), stream);

    const size_t NEED = 269484032ull;  // W1b 268MB + Xb 1MB (bf16, granule order)
    if (ws_size >= NEED) {
        short* WS = (short*)d_ws;
        ens_cvt<<<dim3(4112), dim3(256), 0, stream>>>(X, W1, WS);
        ens_gemm_dma<<<dim3(4096), dim3(512), 131072, stream>>>(
            WS + 134217728ull, WS, B1, W2, B2, out);
    } else {
        ens_mlp_fallback<<<dim3(4096), dim3(512), 131072, stream>>>(
            X, W1, B1, W2, B2, out);
    }
}